// Round 8
// baseline (86.210 us; speedup 1.0000x reference)
//
#include <hip/hip_runtime.h>
#include <cmath>

// ROIAlignV2 multi-level FPN pooler. fp32 in/out.
// R8: demand-masked transpose with full-256ch blocks (512B-contiguous NHWC
// stores, float4 reads) + unified NHWC pool (512B contiguous tap loads).
constexpr int OUTD = 14;
constexpr int NBIN = OUTD * OUTD;   // 196
constexpr int NS   = 28;            // samples per axis
constexpr int CTOT = 256;           // channels

// bf16 ws offsets (ushort elements)
constexpr size_t OFF0 = 0;
constexpr size_t OFF1 = 33554432;        // 2*65536*256
constexpr size_t OFF2 = 41943040;        // OFF1 + 2*16384*256
constexpr size_t OFF3 = 44040192;        // OFF2 + 2*4096*256
constexpr size_t WS_USHORT = 44564480;   // OFF3 + 2*1024*256 (89.1 MB)
// tile flags (bytes), appended after bf16 region
constexpr size_t FLAG_BYTE_OFF = WS_USHORT * 2;
constexpr int F0 = 0, F1 = 2048, F2 = 2560, F3 = 2688;   // per-level offsets
constexpr int FLAG_BYTES = 2720;
constexpr size_t WS_NEED = FLAG_BYTE_OFF + FLAG_BYTES;

__device__ inline int box_level(const float* __restrict__ boxes, int m,
                                float& bx0, float& by0, float& bx1, float& by1)
{
    bx0 = boxes[m*4+0]; by0 = boxes[m*4+1];
    bx1 = boxes[m*4+2]; by1 = boxes[m*4+3];
    const float size = sqrtf((bx1-bx0)*(by1-by0));
    float lf = floorf(4.0f + log2f(size/224.0f + 2.220446049250313e-16f));
    lf = fminf(fmaxf(lf, 2.0f), 5.0f);
    return (int)lf - 2;             // 0..3
}

// touched coordinate range [lo, hi] on one axis (same math as pool taps)
__device__ inline void axis_window(float c0, float c1, int HW, int& lo, int& hi)
{
    const float binw = (c1 - c0) * (1.0f/OUTD);
    const float HWm1 = (float)(HW-1);
    const float pL = fminf(fmaxf(c0 + 0.25f*binw, 0.f), HWm1);   // sample 0
    const float pH = fminf(fmaxf(c0 + 13.75f*binw, 0.f), HWm1);  // sample 27
    lo = (int)floorf(pL);
    hi = min((int)floorf(pH) + 1, HW - 1);
}

__device__ inline float b2f(unsigned short u) {
    return __uint_as_float(((unsigned int)u) << 16);
}

__device__ inline unsigned short f2b(float x) {           // RTNE
    unsigned int u = __float_as_uint(x);
    u = (u + 0x7FFFu + ((u >> 16) & 1u)) >> 16;
    return (unsigned short)u;
}

// ---- Pass M: zero + mark touched tiles (single block) ----
__global__ __launch_bounds__(256) void mark_kernel(
    const float* __restrict__ boxes, const int* __restrict__ bidx,
    unsigned char* __restrict__ flags, int M)
{
    const int t = threadIdx.x;
    for (int i = t; i < FLAG_BYTES; i += 256) flags[i] = 0;
    __syncthreads();
    for (int m = t; m < M; m += 256) {
        float bx0, by0, bx1, by1;
        const int L = box_level(boxes, m, bx0, by0, bx1, by1);
        const int HW = 256 >> L;
        const float scale = (L==0)?0.25f:(L==1)?0.125f:(L==2)?0.0625f:0.03125f;
        const int foff = (L==0)?F0:(L==1)?F1:(L==2)?F2:F3;
        const int ntiles = (HW*HW) >> 6;
        const int b = bidx[m];
        int xlo, xhi, ylo, yhi;
        axis_window(bx0*scale - 0.5f, bx1*scale - 0.5f, HW, xlo, xhi);
        axis_window(by0*scale - 0.5f, by1*scale - 0.5f, HW, ylo, yhi);
        unsigned char* f = flags + foff + b*ntiles;
        for (int y = ylo; y <= yhi; ++y) {
            const int t0 = (y*HW + xlo) >> 6;
            const int t1 = (y*HW + xhi) >> 6;
            for (int ti = t0; ti <= t1; ++ti) f[ti] = 1;
        }
    }
}

// ---- Pass T: masked transpose NCHW fp32 -> NHWC bf16, 256ch x 64px blocks --
// 1024 threads. grid: f0:2048, f1:512, f2:128, f3:32 = 2720
__global__ __launch_bounds__(1024) void transpose_kernel(
    const float* __restrict__ f0, const float* __restrict__ f1,
    const float* __restrict__ f2, const float* __restrict__ f3,
    unsigned short* __restrict__ ws, const unsigned char* __restrict__ flags)
{
    const int id = blockIdx.x;
    const float* src; size_t offs; int HWsq, rem, tshift, foff;
    if (id < 2048)      { src = f0; offs = OFF0; HWsq = 65536; rem = id;        tshift = 10; foff = F0; }
    else if (id < 2560) { src = f1; offs = OFF1; HWsq = 16384; rem = id - 2048; tshift = 8;  foff = F1; }
    else if (id < 2688) { src = f2; offs = OFF2; HWsq = 4096;  rem = id - 2560; tshift = 6;  foff = F2; }
    else                { src = f3; offs = OFF3; HWsq = 1024;  rem = id - 2688; tshift = 4;  foff = F3; }
    const int tile = rem & ((1 << tshift) - 1);
    const int b    = rem >> tshift;
    if (!flags[foff + b*(HWsq >> 6) + tile]) return;
    const int px0  = tile << 6;

    __shared__ unsigned short tl[64][264];   // [px][ch], rows 528B (16B-mult)
    const int t = threadIdx.x;

    const float* s = src + (size_t)b*CTOT*HWsq + px0;
    #pragma unroll
    for (int r = 0; r < 4; ++r) {
        const int ch = r*64 + (t >> 4);      // wave covers 4 ch x 64 px
        const int px = (t & 15) * 4;
        const float4 v = *(const float4*)(s + (size_t)ch*HWsq + px);
        tl[px+0][ch] = f2b(v.x);
        tl[px+1][ch] = f2b(v.y);
        tl[px+2][ch] = f2b(v.z);
        tl[px+3][ch] = f2b(v.w);
    }
    __syncthreads();

    unsigned short* d = ws + offs + ((size_t)b * HWsq + px0) * CTOT;
    #pragma unroll
    for (int r = 0; r < 2; ++r) {
        const int px  = r*32 + (t >> 5);     // 32 lanes cover one px's 256 ch
        const int c16 = (t & 31) * 8;
        const uint4 val = *(const uint4*)&tl[px][c16];
        *(uint4*)(d + (size_t)px*CTOT + c16) = val;   // 512B contiguous / px
    }
}

// ---- Pass P: unified pool, taps from NHWC bf16 ws, lanes over channels ----
__global__ __launch_bounds__(256) void pool_nhwc(
    const float* __restrict__ boxes, const int* __restrict__ bidx,
    const unsigned short* __restrict__ ws, float* __restrict__ out)
{
    const int m  = blockIdx.x;
    const int bb = blockIdx.y;          // bins [28bb, 28bb+28)
    float bx0, by0, bx1, by1;
    const int L = box_level(boxes, m, bx0, by0, bx1, by1);
    const int HW = 256 >> L;
    const float scale = (L==0) ? 0.25f : (L==1) ? 0.125f : (L==2) ? 0.0625f : 0.03125f;
    const size_t offs = (L==0) ? OFF0 : (L==1) ? OFF1 : (L==2) ? OFF2 : OFF3;
    const int b = bidx[m];

    __shared__ int4  s_tab[2][NS];      // absolute {lo, hi, wl, wh}
    __shared__ float obuf[28 * 257];

    const int t = threadIdx.x, wave = t >> 6, lane = t & 63;
    if (t < 2*NS) {
        const int axis = t / NS, s = t % NS;
        const float c0 = (axis ? by0 : bx0) * scale - 0.5f;
        const float c1 = (axis ? by1 : bx1) * scale - 0.5f;
        const float binw = (c1 - c0) * (1.0f/OUTD);
        const float g = (float)(s >> 1) + ((s & 1) ? 0.75f : 0.25f);
        const float p = c0 + g * binw;
        const bool valid = (p > -1.0f) && (p < (float)HW);
        const float pc = fminf(fmaxf(p, 0.0f), (float)(HW - 1));
        const int lo = (int)floorf(pc);
        const int hi = min(lo + 1, HW - 1);
        const float l = pc - (float)lo;
        int4 e; e.x = lo; e.y = hi;
        e.z = __float_as_int(valid ? (1.0f - l) : 0.0f);
        e.w = __float_as_int(valid ? l : 0.0f);
        s_tab[axis][s] = e;
    }
    __syncthreads();

    const unsigned short* mbase = ws + offs + (size_t)b * HW * HW * CTOT;
    const int rowstr = HW * CTOT;

    for (int lb = 7*wave; lb < 7*wave + 7; ++lb) {
        const int bin = 28*bb + lb;
        const int ph = bin / OUTD, pw = bin - ph*OUTD;
        const int4 ty0 = s_tab[1][2*ph], ty1 = s_tab[1][2*ph+1];
        const int4 tx0 = s_tab[0][2*pw], tx1 = s_tab[0][2*pw+1];
        int ro[4]; float wy[4];
        ro[0]=ty0.x*rowstr; wy[0]=__int_as_float(ty0.z);
        ro[1]=ty0.y*rowstr; wy[1]=__int_as_float(ty0.w);
        ro[2]=ty1.x*rowstr; wy[2]=__int_as_float(ty1.z);
        ro[3]=ty1.y*rowstr; wy[3]=__int_as_float(ty1.w);
        int co[4]; float wx[4];
        co[0]=tx0.x*CTOT; wx[0]=__int_as_float(tx0.z);
        co[1]=tx0.y*CTOT; wx[1]=__int_as_float(tx0.w);
        co[2]=tx1.x*CTOT; wx[2]=__int_as_float(tx1.z);
        co[3]=tx1.y*CTOT; wx[3]=__int_as_float(tx1.w);

        ushort4 v[16]; float wt[16];
        #pragma unroll
        for (int k = 0; k < 16; ++k) {
            const unsigned short* p = mbase + (size_t)(ro[k>>2] + co[k&3]) + 4*lane;
            v[k] = *(const ushort4*)p;
            wt[k] = wy[k>>2] * wx[k&3];
        }
        float4 a0, a1, a2, a3;
        a0.x=a0.y=a0.z=a0.w=0.f; a1=a0; a2=a0; a3=a0;
        #pragma unroll
        for (int k = 0; k < 16; k += 4) {
            a0.x=fmaf(wt[k],  b2f(v[k].x),  a0.x); a0.y=fmaf(wt[k],  b2f(v[k].y),  a0.y);
            a0.z=fmaf(wt[k],  b2f(v[k].z),  a0.z); a0.w=fmaf(wt[k],  b2f(v[k].w),  a0.w);
            a1.x=fmaf(wt[k+1],b2f(v[k+1].x),a1.x); a1.y=fmaf(wt[k+1],b2f(v[k+1].y),a1.y);
            a1.z=fmaf(wt[k+1],b2f(v[k+1].z),a1.z); a1.w=fmaf(wt[k+1],b2f(v[k+1].w),a1.w);
            a2.x=fmaf(wt[k+2],b2f(v[k+2].x),a2.x); a2.y=fmaf(wt[k+2],b2f(v[k+2].y),a2.y);
            a2.z=fmaf(wt[k+2],b2f(v[k+2].z),a2.z); a2.w=fmaf(wt[k+2],b2f(v[k+2].w),a2.w);
            a3.x=fmaf(wt[k+3],b2f(v[k+3].x),a3.x); a3.y=fmaf(wt[k+3],b2f(v[k+3].y),a3.y);
            a3.z=fmaf(wt[k+3],b2f(v[k+3].z),a3.z); a3.w=fmaf(wt[k+3],b2f(v[k+3].w),a3.w);
        }
        a0.x += a1.x + a2.x + a3.x;  a0.y += a1.y + a2.y + a3.y;
        a0.z += a1.z + a2.z + a3.z;  a0.w += a1.w + a2.w + a3.w;
        float* ob = obuf + lb*257;
        ob[4*lane+0] = a0.x*0.25f; ob[4*lane+1] = a0.y*0.25f;
        ob[4*lane+2] = a0.z*0.25f; ob[4*lane+3] = a0.w*0.25f;
    }
    __syncthreads();

    // obuf [28][256] -> out [c][bin]: bin-contiguous stores
    for (int s = t; s < 28*CTOT; s += 256) {
        const int c = s / 28, bp = s - 28*c;
        out[((size_t)(m*CTOT + c))*NBIN + 28*bb + bp] = obuf[bp*257 + c];
    }
}

// ---- fallback: direct gather (R2-proven), all boxes ----
__global__ __launch_bounds__(256) void roi_pool_direct(
    const float* __restrict__ f0, const float* __restrict__ f1,
    const float* __restrict__ f2, const float* __restrict__ f3,
    const float* __restrict__ boxes, const int* __restrict__ bidx,
    float* __restrict__ out)
{
    const int m  = blockIdx.x;
    const int cg = blockIdx.y;
    float bx0, by0, bx1, by1;
    const int L = box_level(boxes, m, bx0, by0, bx1, by1);
    const float scale = (L==0)?0.25f:(L==1)?0.125f:(L==2)?0.0625f:0.03125f;
    const int HW = 256 >> L;
    const float* feat = (L==0)?f0:(L==1)?f1:(L==2)?f2:f3;
    const int b = bidx[m];

    __shared__ int4 s_tab[2][NS];
    const int t = threadIdx.x;
    if (t < 2*NS) {
        const int axis = t / NS, s = t % NS;
        const float c0 = (axis ? by0 : bx0) * scale - 0.5f;
        const float c1 = (axis ? by1 : bx1) * scale - 0.5f;
        const float binw = (c1 - c0) * (1.0f/OUTD);
        const float g = (float)(s >> 1) + ((s & 1) ? 0.75f : 0.25f);
        const float p = c0 + g * binw;
        const bool valid = (p > -1.0f) && (p < (float)HW);
        const float pc = fminf(fmaxf(p, 0.0f), (float)(HW - 1));
        const int lo = (int)floorf(pc);
        const int hi = min(lo + 1, HW - 1);
        const float l = pc - (float)lo;
        int4 e; e.x = lo; e.y = hi;
        e.z = __float_as_int(valid ? (1.0f - l) : 0.0f);
        e.w = __float_as_int(valid ? l : 0.0f);
        s_tab[axis][s] = e;
    }
    __syncthreads();

    const int W = HW;
    const size_t cs = (size_t)HW*HW;
    const float* gbase = feat + (size_t)(b*CTOT + cg*32)*cs;
    for (int i = t; i < 16*NBIN; i += 256) {
        const int cl = i / NBIN, bin = i - cl*NBIN;
        const int ph = bin / OUTD, pw = bin - ph*OUTD;
        const int4 ty0 = s_tab[1][2*ph], ty1 = s_tab[1][2*ph+1];
        const int4 tx0 = s_tab[0][2*pw], tx1 = s_tab[0][2*pw+1];
        int rs[4]; float wy[4];
        rs[0]=ty0.x*W; wy[0]=__int_as_float(ty0.z);
        rs[1]=ty0.y*W; wy[1]=__int_as_float(ty0.w);
        rs[2]=ty1.x*W; wy[2]=__int_as_float(ty1.z);
        rs[3]=ty1.y*W; wy[3]=__int_as_float(ty1.w);
        int cx[4]; float wx[4];
        cx[0]=tx0.x; wx[0]=__int_as_float(tx0.z);
        cx[1]=tx0.y; wx[1]=__int_as_float(tx0.w);
        cx[2]=tx1.x; wx[2]=__int_as_float(tx1.z);
        cx[3]=tx1.y; wx[3]=__int_as_float(tx1.w);
        const float* b0 = gbase + (size_t)cl*cs;
        const float* b1 = b0 + (size_t)16*cs;
        float v0[16], v1[16], w[16];
        #pragma unroll
        for (int k = 0; k < 16; ++k) {
            const int off = rs[k>>2] + cx[k&3];
            v0[k] = b0[off]; v1[k] = b1[off];
            w[k] = wy[k>>2]*wx[k&3];
        }
        float A0=0.f, A1=0.f;
        #pragma unroll
        for (int k = 0; k < 16; ++k) { A0 += w[k]*v0[k]; A1 += w[k]*v1[k]; }
        const size_t ob = ((size_t)m*CTOT + cg*32 + cl)*NBIN + bin;
        out[ob] = A0*0.25f;
        out[ob + (size_t)16*NBIN] = A1*0.25f;
    }
}

extern "C" void kernel_launch(void* const* d_in, const int* in_sizes, int n_in,
                              void* d_out, int out_size, void* d_ws, size_t ws_size,
                              hipStream_t stream) {
    const float* f0    = (const float*)d_in[0];
    const float* f1    = (const float*)d_in[1];
    const float* f2    = (const float*)d_in[2];
    const float* f3    = (const float*)d_in[3];
    const float* boxes = (const float*)d_in[4];
    const int*   bidx  = (const int*)d_in[5];
    float* out = (float*)d_out;

    const int M = in_sizes[5];
    if (ws_size >= WS_NEED) {
        unsigned short* ws = (unsigned short*)d_ws;
        unsigned char* flags = (unsigned char*)d_ws + FLAG_BYTE_OFF;
        mark_kernel<<<1, 256, 0, stream>>>(boxes, bidx, flags, M);
        transpose_kernel<<<2720, 1024, 0, stream>>>(f0, f1, f2, f3, ws, flags);
        pool_nhwc<<<dim3(M, 7), 256, 0, stream>>>(boxes, bidx, ws, out);
    } else {
        roi_pool_direct<<<dim3(M, 8), 256, 0, stream>>>(f0,f1,f2,f3,boxes,bidx,out);
    }
}